// Round 6
// baseline (169.009 us; speedup 1.0000x reference)
//
#include <hip/hip_runtime.h>
#include <stdint.h>

// Exactness: the numpy/jax reference does plain IEEE f32 ops (no FMA
// contraction). hipcc defaults to -ffp-contract=fast; disable globally so
// IoU values match the reference bit-for-bit (labels depend on exact
// comparisons vs 0.3/0.7 and on ov == gt_max equality).
#pragma clang fp contract(off)

#define NBATCH 32
#define NK 50
#define NH 64
#define NW 64
#define NA 9
#define NN (NH * NW * NA)   // 36864 anchors per batch
#define BN (NBATCH * NN)    // 1179648
#define HWSZ (NH * NW)      // 4096
#define LBLK_PER_B (NN / 1024)  // 36 label-blocks per batch (4 anchors/thread)

// ---------------- workspace layout (bytes) ----------------
// pk[t] = (v23 << 2) | (lab+1): 23-bit threefry score + 2-bit label code,
// computed once in k_label (massively parallel) so k_select never hashes.
constexpr size_t OFF_AMAX  = 0;
constexpr size_t OFF_PK    = OFF_AMAX + (size_t)BN * 4;
constexpr size_t OFF_GTMAX = OFF_PK + (size_t)BN * 4;
constexpr size_t OFF_NUMEX = OFF_GTMAX + (size_t)NBATCH * NK * 4;

// ---------------- output layout (f32 elements) ----------------
constexpr size_t OUT_LAB  = 0;
constexpr size_t OUT_TGT  = (size_t)NBATCH * NA * HWSZ;                 // 1179648
constexpr size_t OUT_INW  = OUT_TGT + (size_t)NBATCH * NA * 4 * HWSZ;   // 5898240
constexpr size_t OUT_OUTW = OUT_INW + (size_t)NBATCH * NA * 4 * HWSZ;   // 10616832

// 9 base anchors, py-faster-rcnn generate_anchors(16, (0.5,1,2), (8,16,32)),
// ratio-major scale-minor. All integer-valued -> exact in f32.
__constant__ float c_anch[NA][4] = {
    {-84.f, -40.f, 99.f, 55.f},    {-176.f, -88.f, 191.f, 103.f},
    {-360.f, -184.f, 375.f, 199.f}, {-56.f, -56.f, 71.f, 71.f},
    {-120.f, -120.f, 135.f, 135.f}, {-248.f, -248.f, 263.f, 263.f},
    {-36.f, -80.f, 51.f, 95.f},    {-80.f, -168.f, 95.f, 183.f},
    {-168.f, -344.f, 183.f, 359.f}};

// ---------------- Threefry-2x32 (JAX convention) ----------------
struct TF2 { uint32_t a, b; };

__host__ __device__ constexpr uint32_t rotl32(uint32_t x, int d) {
  return (x << d) | (x >> (32 - d));
}

__host__ __device__ constexpr TF2 threefry2x32(uint32_t k0, uint32_t k1,
                                               uint32_t x0, uint32_t x1) {
  uint32_t ks2 = k0 ^ k1 ^ 0x1BD11BDAu;
  x0 += k0; x1 += k1;
  x0 += x1; x1 = rotl32(x1, 13); x1 ^= x0;
  x0 += x1; x1 = rotl32(x1, 15); x1 ^= x0;
  x0 += x1; x1 = rotl32(x1, 26); x1 ^= x0;
  x0 += x1; x1 = rotl32(x1, 6);  x1 ^= x0;
  x0 += k1; x1 += ks2 + 1u;
  x0 += x1; x1 = rotl32(x1, 17); x1 ^= x0;
  x0 += x1; x1 = rotl32(x1, 29); x1 ^= x0;
  x0 += x1; x1 = rotl32(x1, 16); x1 ^= x0;
  x0 += x1; x1 = rotl32(x1, 24); x1 ^= x0;
  x0 += ks2; x1 += k0 + 2u;
  x0 += x1; x1 = rotl32(x1, 13); x1 ^= x0;
  x0 += x1; x1 = rotl32(x1, 15); x1 ^= x0;
  x0 += x1; x1 = rotl32(x1, 26); x1 ^= x0;
  x0 += x1; x1 = rotl32(x1, 6);  x1 ^= x0;
  x0 += k0; x1 += k1 + 3u;
  x0 += x1; x1 = rotl32(x1, 17); x1 ^= x0;
  x0 += x1; x1 = rotl32(x1, 29); x1 ^= x0;
  x0 += x1; x1 = rotl32(x1, 16); x1 ^= x0;
  x0 += x1; x1 = rotl32(x1, 24); x1 ^= x0;
  x0 += k1; x1 += ks2 + 4u;
  x0 += x1; x1 = rotl32(x1, 13); x1 ^= x0;
  x0 += x1; x1 = rotl32(x1, 15); x1 ^= x0;
  x0 += x1; x1 = rotl32(x1, 26); x1 ^= x0;
  x0 += x1; x1 = rotl32(x1, 6);  x1 ^= x0;
  x0 += ks2; x1 += k0 + 5u;
  return TF2{x0, x1};
}

// jax.random.key(42) = (0,42); split with jax_threefry_partitionable=True:
// subkey i = threefry(key, counter=(0, i)).
constexpr TF2 KEY_FG = threefry2x32(0u, 42u, 0u, 0u);
constexpr TF2 KEY_BG = threefry2x32(0u, 42u, 0u, 1u);

// 32-bit draw at flat index i (partitionable): bits = out.a ^ out.b of
// threefry(key, hi32(i)=0, lo32(i)=i). Ranking score for uniform() is
// monotone+injective in bits>>9, so compare the 23-bit value directly.
__device__ inline uint32_t rand23(uint32_t k0, uint32_t k1, uint32_t idx) {
  TF2 r = threefry2x32(k0, k1, 0u, idx);
  return (r.a ^ r.b) >> 9;
}

// ---------------- geometry ----------------
__device__ inline void anchor_of(int n, float& x1, float& y1, float& x2, float& y2) {
  int a = n % NA;
  int s = n / NA;
  int xx = s % NW;
  int yy = s / NW;
  float sx = (float)(xx * 16);
  float sy = (float)(yy * 16);
  x1 = c_anch[a][0] + sx; y1 = c_anch[a][1] + sy;
  x2 = c_anch[a][2] + sx; y2 = c_anch[a][3] + sy;
}

__device__ inline float iou1(float ax1, float ay1, float ax2, float ay2,
                             float gx1, float gy1, float gx2, float gy2) {
  float iw = fminf(ax2, gx2) - fmaxf(ax1, gx1) + 1.0f;
  iw = fmaxf(iw, 0.0f);
  float ih = fminf(ay2, gy2) - fmaxf(ay1, gy1) + 1.0f;
  ih = fmaxf(ih, 0.0f);
  float inter = iw * ih;
  float aa = (ax2 - ax1 + 1.0f) * (ay2 - ay1 + 1.0f);
  float ga = (gx2 - gx1 + 1.0f) * (gy2 - gy1 + 1.0f);
  return inter / (aa + ga - inter);
}

// ---------------- K1: per-gt max IoU, pruned to overlapping cells -------
// Anchors with no box overlap have iou exactly 0 and cannot affect the max
// (if the pruned max is 0, the reference's gt_max==0 -> 1e-5 replacement
// makes the best-check vacuous anyway). Per anchor type, overlapping shift
// cells form a rectangle; scan it with pow2-padded rows (shift/mask index
// math, conservative +/-1 cell margin). ~6.5K cells/gt vs 36864 brute.
__global__ __launch_bounds__(256) void k_gtmax(const float* __restrict__ gt,
                                               const int* __restrict__ nbox,
                                               float* __restrict__ gtmax) {
  int b = blockIdx.x / NK;
  int k = blockIdx.x % NK;
  if (k >= nbox[b]) {
    if (threadIdx.x == 0) gtmax[blockIdx.x] = -1.0f;  // unused downstream
    return;
  }
  const float* g = gt + ((size_t)b * NK + k) * 5;
  float gx1 = g[0], gy1 = g[1], gx2 = g[2], gy2 = g[3];
  float m = 0.0f;  // iou >= 0; empty scan -> 0 -> 1e-5 below
#pragma unroll
  for (int a = 0; a < NA; ++a) {
    float bx1 = c_anch[a][0], by1 = c_anch[a][1];
    float bx2 = c_anch[a][2], by2 = c_anch[a][3];
    // overlap needs 16*ix > gx1-1-bx2  and  16*ix < gx2+1-bx1 (cons. +/-1)
    int ix_lo = max(0, (int)floorf((gx1 - 1.0f - bx2) * 0.0625f) - 1);
    int ix_hi = min(NW - 1, (int)ceilf((gx2 + 1.0f - bx1) * 0.0625f) + 1);
    int iy_lo = max(0, (int)floorf((gy1 - 1.0f - by2) * 0.0625f) - 1);
    int iy_hi = min(NH - 1, (int)ceilf((gy2 + 1.0f - by1) * 0.0625f) + 1);
    if (ix_lo > ix_hi || iy_lo > iy_hi) continue;
    int nx = ix_hi - ix_lo + 1;
    int ny = iy_hi - iy_lo + 1;
    int lg = 32 - __clz(nx - 1);        // nx<=64 -> lg<=6 (nx==1 -> lg=0)
    int tot = ny << lg;
    unsigned mask = (1u << lg) - 1u;
    for (int c = threadIdx.x; c < tot; c += 256) {
      int ixo = c & mask;
      if (ixo >= nx) continue;
      int ix = ix_lo + ixo;
      int iy = iy_lo + (c >> lg);
      float sx = (float)(ix * 16), sy = (float)(iy * 16);
      m = fmaxf(m, iou1(bx1 + sx, by1 + sy, bx2 + sx, by2 + sy, gx1, gy1, gx2, gy2));
    }
  }
  for (int o = 1; o < 64; o <<= 1) m = fmaxf(m, __shfl_xor(m, o));
  __shared__ float ws4[4];
  if ((threadIdx.x & 63) == 0) ws4[threadIdx.x >> 6] = m;
  __syncthreads();
  if (threadIdx.x == 0) {
    m = fmaxf(fmaxf(ws4[0], ws4[1]), fmaxf(ws4[2], ws4[3]));
    if (m == 0.0f) m = 1e-5f;  // reference: gt_max==0 -> 1e-5
    gtmax[blockIdx.x] = m;
  }
}

// ---------------- K2: IoU + labels + threefry score, packed write -------
// 4 consecutive anchors per thread: the 5 wave-uniform LDS reads per gt box
// now feed 4 IoUs (ds_read cost /4 — was the kernel's bottleneck), and
// pk/amax become uint4/int4 stores. IoU arithmetic per anchor unchanged.
__global__ __launch_bounds__(256) void k_label(const float* __restrict__ gt,
                                               const int* __restrict__ nbox,
                                               const float* __restrict__ gtmax,
                                               const float* __restrict__ iminfo,
                                               unsigned* __restrict__ pkarr,
                                               int* __restrict__ amax) {
  int b = blockIdx.x / LBLK_PER_B;               // block-uniform batch index
  int n0 = (blockIdx.x % LBLK_PER_B) * 1024 + threadIdx.x * 4;
  __shared__ float sg[NK * 5];
  __shared__ float sgm[NK];
  __shared__ float sga[NK];
  if (threadIdx.x < NK * 5) sg[threadIdx.x] = gt[(size_t)b * NK * 5 + threadIdx.x];
  if (threadIdx.x < NK) sgm[threadIdx.x] = gtmax[b * NK + threadIdx.x];
  __syncthreads();
  if (threadIdx.x < NK) {
    float* gg = sg + threadIdx.x * 5;
    sga[threadIdx.x] = (gg[2] - gg[0] + 1.0f) * (gg[3] - gg[1] + 1.0f);
  }
  __syncthreads();

  float ax1[4], ay1[4], ax2[4], ay2[4], aa[4], best[4];
  int bi[4];
  bool isb[4];
#pragma unroll
  for (int u = 0; u < 4; ++u) {
    anchor_of(n0 + u, ax1[u], ay1[u], ax2[u], ay2[u]);
    aa[u] = (ax2[u] - ax1[u] + 1.0f) * (ay2[u] - ay1[u] + 1.0f);
    best[u] = -2.0f; bi[u] = 0; isb[u] = false;
  }
  int m = nbox[b];
  for (int k = 0; k < m; ++k) {
    float gx1 = sg[k * 5], gy1 = sg[k * 5 + 1];
    float gx2 = sg[k * 5 + 2], gy2 = sg[k * 5 + 3];
    float ga = sga[k], gm = sgm[k];
#pragma unroll
    for (int u = 0; u < 4; ++u) {
      float iw = fminf(ax2[u], gx2) - fmaxf(ax1[u], gx1) + 1.0f;
      iw = fmaxf(iw, 0.0f);
      float ih = fminf(ay2[u], gy2) - fmaxf(ay1[u], gy1) + 1.0f;
      ih = fmaxf(ih, 0.0f);
      float inter = iw * ih;
      float ov = inter / (aa[u] + ga - inter);
      if (ov > best[u]) { best[u] = ov; bi[u] = k; }  // first-max wins
      isb[u] = isb[u] | (ov == gm);
    }
  }
  float imh = iminfo[0], imw = iminfo[1];  // im_info[0] for all batches (ref)
  unsigned pkv[4];
#pragma unroll
  for (int u = 0; u < 4; ++u) {
    bool inside = (ax1[u] >= 0.0f) && (ay1[u] >= 0.0f) &&
                  (ax2[u] < imw) && (ay2[u] < imh);
    int lab = -1;
    if (inside) {
      if (best[u] < 0.3f) lab = 0;
      if (isb[u]) lab = 1;
      if (best[u] >= 0.7f) lab = 1;
    }
    uint32_t kk0 = (lab == 1) ? KEY_FG.a : KEY_BG.a;
    uint32_t kk1 = (lab == 1) ? KEY_FG.b : KEY_BG.b;
    uint32_t v = rand23(kk0, kk1, (uint32_t)(b * NN + n0 + u));
    pkv[u] = (v << 2) | (uint32_t)(lab + 1);
  }
  int t0 = b * NN + n0;
  *(uint4*)(pkarr + t0) = make_uint4(pkv[0], pkv[1], pkv[2], pkv[3]);
  *(int4*)(amax + t0) = make_int4(bi[0], bi[1], bi[2], bi[3]);
}

// ---------------- K3: exact stable top-C subsampling -------------------
// One 1024-thread block per (batch, class). Reads pre-hashed pk words:
//   P1: count fg/bg + 4096-bucket LDS histogram (bucket = pk>>13).
//   (parallel suffix-scan finds threshold bucket Bs and within-bucket rank r1)
//   P2: demote bucket<Bs inline; collect bucket==Bs ties into an LDS list.
// Exact stable top-r1 among ties by (v desc, idx asc) via O(L^2) rank.
// Benign race note: concurrent fg-block demotions only move the bg block's
// observed fg count between fg and fgk=min(fg,128); min(.,128) is invariant,
// so C and numex are unaffected. Demotes only clear the 2 code bits.
__global__ __launch_bounds__(1024) void k_select(unsigned* __restrict__ pkarr,
                                                 float* __restrict__ numex) {
  int b = blockIdx.x >> 1;
  int cls = blockIdx.x & 1;  // 0 = fg, 1 = bg
  int base_lab = b * NN;
  unsigned wantcode = (cls == 0) ? 2u : 1u;
  int tid = threadIdx.x;

  __shared__ unsigned h1s[4096];
  __shared__ unsigned listV[2048];
  __shared__ unsigned listI[2048];
  __shared__ unsigned waveTot[4];
  __shared__ int sFG, sBG, sBs, sR1, sCross;
  __shared__ unsigned sCnt;
  for (int i = tid; i < 4096; i += 1024) h1s[i] = 0;
  if (tid == 0) { sFG = 0; sBG = 0; sCross = -1; sCnt = 0; }
  __syncthreads();

  const uint4* pk4 = (const uint4*)(pkarr + base_lab);

  // ---- Pass 1: fg/bg counts + level-1 histogram ----
  int cfg = 0, cbg = 0;
  for (int i = tid; i < NN / 4; i += 1024) {
    uint4 P4 = pk4[i];
    unsigned pks[4] = {P4.x, P4.y, P4.z, P4.w};
#pragma unroll
    for (int j = 0; j < 4; ++j) {
      unsigned code = pks[j] & 3u;
      cfg += (code == 2u);
      cbg += (code == 1u);
      if (code == wantcode) atomicAdd(&h1s[pks[j] >> 13], 1u);
    }
  }
  for (int o = 1; o < 64; o <<= 1) { cfg += __shfl_xor(cfg, o); cbg += __shfl_xor(cbg, o); }
  if ((tid & 63) == 0) { atomicAdd(&sFG, cfg); atomicAdd(&sBG, cbg); }
  __syncthreads();

  int fg = sFG, bg = sBG;
  int fgk = min(fg, 128);
  int total, C;
  if (cls == 0) {
    total = fg; C = 128;
  } else {
    total = bg; C = 256 - fgk;
    if (tid == 0) numex[b] = (float)(fgk + min(bg, C));  // analytic num_examples
  }
  if (total <= C) return;  // keep all; uniform exit across block

  // ---- Parallel threshold: largest bucket Bs with suffix count >= C ----
  unsigned myChunk = 0, suf = 0;
  if (tid < 256) {
    for (int j = 0; j < 16; ++j) myChunk += h1s[tid * 16 + j];
    unsigned ss = myChunk;
    int lane = tid & 63;
#pragma unroll
    for (int o = 1; o < 64; o <<= 1) {
      unsigned t2 = __shfl_down(ss, o);
      if (lane + o < 64) ss += t2;
    }
    suf = ss;  // partial: suffix within this wave's chunk range
    if (lane == 0) waveTot[tid >> 6] = ss;
  }
  __syncthreads();
  if (tid < 256) {
    int w = tid >> 6;
    for (int w2 = w + 1; w2 < 4; ++w2) suf += waveTot[w2];
    // suf = S[16*tid] = count of scores in buckets >= 16*tid
    if (suf >= (unsigned)C) atomicMax(&sCross, tid);
  }
  __syncthreads();
  if (tid == sCross) {
    unsigned cum = suf - myChunk;  // S[16*(tid+1)]
    int i = tid * 16 + 15;
    for (;; --i) {
      unsigned c = h1s[i];
      if (cum + c >= (unsigned)C) break;
      cum += c;
    }
    sBs = i; sR1 = (int)((unsigned)C - cum);
  }
  __syncthreads();
  int Bs = sBs;
  unsigned r1 = (unsigned)sR1;

  // ---- Pass 2: demote bucket<Bs, collect bucket==Bs ties ----
  for (int i = tid; i < NN / 4; i += 1024) {
    uint4 P4 = pk4[i];
    unsigned pks[4] = {P4.x, P4.y, P4.z, P4.w};
#pragma unroll
    for (int j = 0; j < 4; ++j) {
      if ((pks[j] & 3u) == wantcode) {
        unsigned v = pks[j] >> 2;
        int bk = (int)(v >> 11);
        int n = 4 * i + j;
        if (bk < Bs) {
          pkarr[base_lab + n] = pks[j] & ~3u;  // lab -> -1, keep v bits
        } else if (bk == Bs) {
          unsigned p = atomicAdd(&sCnt, 1u);
          if (p < 2048u) { listV[p] = v; listI[p] = (unsigned)n; }
        }
      }
    }
  }
  __syncthreads();

  // ---- Exact stable top-r1 among ties: rank by (v desc, idx asc) ----
  unsigned L = min(sCnt, 2048u);
  for (unsigned i = tid; i < L; i += 1024) {
    unsigned vi = listV[i], xi = listI[i];
    unsigned rank = 0;
    for (unsigned j = 0; j < L; ++j) {
      unsigned vj = listV[j], xj = listI[j];
      rank += (vj > vi) || (vj == vi && xj < xi);
    }
    if (rank >= r1) pkarr[base_lab + (int)xi] = vi << 2;  // demote tie
  }
}

// ---------------- K4: write all four outputs (float4 stores) ----------
__global__ __launch_bounds__(256) void k_out(const float* __restrict__ gt,
                                             const unsigned* __restrict__ pkarr,
                                             const int* __restrict__ amax,
                                             const float* __restrict__ iminfo,
                                             const float* __restrict__ numex,
                                             float* __restrict__ out) {
  int q = blockIdx.x * 256 + threadIdx.x;
  if (q >= (int)(OUT_TGT / 4)) return;
  int xx4 = q & 15;
  int yy = (q >> 4) & 63;
  int ba = q >> 10;
  int a = ba % NA;
  int b = ba / NA;
  int xx0 = xx4 * 4;
  int yx0 = yy * NW + xx0;

  float imh = iminfo[0], imw = iminfo[1];
  float inv_ne = 1.0f / numex[b];

  float labf[4], iwv[4], owv[4], tg[4][4];
#pragma unroll
  for (int u = 0; u < 4; ++u) {
    int xx = xx0 + u;
    int n = (yy * NW + xx) * NA + a;
    int bn = b * NN + n;
    int lab = (int)(pkarr[bn] & 3u) - 1;
    labf[u] = (float)lab;
    float ax1, ay1, ax2, ay2;
    anchor_of(n, ax1, ay1, ax2, ay2);
    bool inside = (ax1 >= 0.0f) && (ay1 >= 0.0f) && (ax2 < imw) && (ay2 < imh);
    float t0 = 0.f, t1 = 0.f, t2 = 0.f, t3 = 0.f;
    if (inside) {
      const float* g = gt + ((size_t)b * NK + amax[bn]) * 5;
      float ew = ax2 - ax1 + 1.0f, eh = ay2 - ay1 + 1.0f;
      float ecx = ax1 + 0.5f * ew, ecy = ay1 + 0.5f * eh;
      float gw = g[2] - g[0] + 1.0f, gh = g[3] - g[1] + 1.0f;
      float gcx = g[0] + 0.5f * gw, gcy = g[1] + 0.5f * gh;
      t0 = (gcx - ecx) / ew;
      t1 = (gcy - ecy) / eh;
      t2 = logf(gw / ew);
      t3 = logf(gh / eh);
    }
    tg[0][u] = t0; tg[1][u] = t1; tg[2][u] = t2; tg[3][u] = t3;
    iwv[u] = (lab == 1) ? 1.0f : 0.0f;
    owv[u] = (lab >= 0) ? inv_ne : 0.0f;
  }

  *(float4*)(out + OUT_LAB + (size_t)ba * HWSZ + yx0) =
      make_float4(labf[0], labf[1], labf[2], labf[3]);
  size_t tb = OUT_TGT + ((size_t)b * NA * 4 + a * 4) * HWSZ + yx0;
#pragma unroll
  for (int d = 0; d < 4; ++d)
    *(float4*)(out + tb + (size_t)d * HWSZ) =
        make_float4(tg[d][0], tg[d][1], tg[d][2], tg[d][3]);
  size_t ib = OUT_INW + ((size_t)b * NA * 4 + a * 4) * HWSZ + yx0;
  float4 iw4 = make_float4(iwv[0], iwv[1], iwv[2], iwv[3]);
#pragma unroll
  for (int d = 0; d < 4; ++d) *(float4*)(out + ib + (size_t)d * HWSZ) = iw4;
  size_t ob = OUT_OUTW + ((size_t)b * NA * 4 + a * 4) * HWSZ + yx0;
  float4 ow4 = make_float4(owv[0], owv[1], owv[2], owv[3]);
#pragma unroll
  for (int d = 0; d < 4; ++d) *(float4*)(out + ob + (size_t)d * HWSZ) = ow4;
}

extern "C" void kernel_launch(void* const* d_in, const int* in_sizes, int n_in,
                              void* d_out, int out_size, void* d_ws, size_t ws_size,
                              hipStream_t stream) {
  (void)in_sizes; (void)n_in; (void)out_size; (void)ws_size;
  const float* gt     = (const float*)d_in[1];  // (B,K,5)
  const float* iminfo = (const float*)d_in[2];  // (B,3)
  const int*   nbox   = (const int*)d_in[3];    // (B,)
  float* out = (float*)d_out;
  char* ws = (char*)d_ws;

  int*      amax  = (int*)(ws + OFF_AMAX);
  unsigned* pkarr = (unsigned*)(ws + OFF_PK);
  float*    gtmax = (float*)(ws + OFF_GTMAX);
  float*    numex = (float*)(ws + OFF_NUMEX);

  k_gtmax<<<NBATCH * NK, 256, 0, stream>>>(gt, nbox, gtmax);
  k_label<<<BN / 1024, 256, 0, stream>>>(gt, nbox, gtmax, iminfo, pkarr, amax);
  k_select<<<2 * NBATCH, 1024, 0, stream>>>(pkarr, numex);
  k_out<<<(int)(OUT_TGT / 4 / 256), 256, 0, stream>>>(gt, pkarr, amax, iminfo, numex, out);
}

// Round 7
// 162.816 us; speedup vs baseline: 1.0380x; 1.0380x over previous
//
#include <hip/hip_runtime.h>
#include <stdint.h>

// Exactness: the numpy/jax reference does plain IEEE f32 ops (no FMA
// contraction). hipcc defaults to -ffp-contract=fast; disable globally so
// IoU values match the reference bit-for-bit (labels depend on exact
// comparisons vs 0.3/0.7 and on ov == gt_max equality).
#pragma clang fp contract(off)

#define NBATCH 32
#define NK 50
#define NH 64
#define NW 64
#define NA 9
#define NN (NH * NW * NA)   // 36864 anchors per batch
#define BN (NBATCH * NN)    // 1179648
#define HWSZ (NH * NW)      // 4096
#define BLK_PER_B (NN / 256)  // 144 label-blocks per batch

// ---------------- workspace layout (bytes) ----------------
// pk[t] = (v23 << 2) | (lab+1). k_select is READ-ONLY on pk; it emits one
// uint4 threshold pair per batch (vfg*, ifg*, vbg*, ibg*) and numex.
constexpr size_t OFF_AMAX  = 0;
constexpr size_t OFF_PK    = OFF_AMAX + (size_t)BN * 4;
constexpr size_t OFF_GTMAX = OFF_PK + (size_t)BN * 4;
constexpr size_t OFF_NUMEX = OFF_GTMAX + (size_t)NBATCH * NK * 4;
constexpr size_t OFF_THR   = OFF_NUMEX + (size_t)NBATCH * 4;

// ---------------- output layout (f32 elements) ----------------
constexpr size_t OUT_LAB  = 0;
constexpr size_t OUT_TGT  = (size_t)NBATCH * NA * HWSZ;                 // 1179648
constexpr size_t OUT_INW  = OUT_TGT + (size_t)NBATCH * NA * 4 * HWSZ;   // 5898240
constexpr size_t OUT_OUTW = OUT_INW + (size_t)NBATCH * NA * 4 * HWSZ;   // 10616832

// 9 base anchors, py-faster-rcnn generate_anchors(16, (0.5,1,2), (8,16,32)),
// ratio-major scale-minor. All integer-valued -> exact in f32.
__constant__ float c_anch[NA][4] = {
    {-84.f, -40.f, 99.f, 55.f},    {-176.f, -88.f, 191.f, 103.f},
    {-360.f, -184.f, 375.f, 199.f}, {-56.f, -56.f, 71.f, 71.f},
    {-120.f, -120.f, 135.f, 135.f}, {-248.f, -248.f, 263.f, 263.f},
    {-36.f, -80.f, 51.f, 95.f},    {-80.f, -168.f, 95.f, 183.f},
    {-168.f, -344.f, 183.f, 359.f}};

// ---------------- Threefry-2x32 (JAX convention) ----------------
struct TF2 { uint32_t a, b; };

__host__ __device__ constexpr uint32_t rotl32(uint32_t x, int d) {
  return (x << d) | (x >> (32 - d));
}

__host__ __device__ constexpr TF2 threefry2x32(uint32_t k0, uint32_t k1,
                                               uint32_t x0, uint32_t x1) {
  uint32_t ks2 = k0 ^ k1 ^ 0x1BD11BDAu;
  x0 += k0; x1 += k1;
  x0 += x1; x1 = rotl32(x1, 13); x1 ^= x0;
  x0 += x1; x1 = rotl32(x1, 15); x1 ^= x0;
  x0 += x1; x1 = rotl32(x1, 26); x1 ^= x0;
  x0 += x1; x1 = rotl32(x1, 6);  x1 ^= x0;
  x0 += k1; x1 += ks2 + 1u;
  x0 += x1; x1 = rotl32(x1, 17); x1 ^= x0;
  x0 += x1; x1 = rotl32(x1, 29); x1 ^= x0;
  x0 += x1; x1 = rotl32(x1, 16); x1 ^= x0;
  x0 += x1; x1 = rotl32(x1, 24); x1 ^= x0;
  x0 += ks2; x1 += k0 + 2u;
  x0 += x1; x1 = rotl32(x1, 13); x1 ^= x0;
  x0 += x1; x1 = rotl32(x1, 15); x1 ^= x0;
  x0 += x1; x1 = rotl32(x1, 26); x1 ^= x0;
  x0 += x1; x1 = rotl32(x1, 6);  x1 ^= x0;
  x0 += k0; x1 += k1 + 3u;
  x0 += x1; x1 = rotl32(x1, 17); x1 ^= x0;
  x0 += x1; x1 = rotl32(x1, 29); x1 ^= x0;
  x0 += x1; x1 = rotl32(x1, 16); x1 ^= x0;
  x0 += x1; x1 = rotl32(x1, 24); x1 ^= x0;
  x0 += k1; x1 += ks2 + 4u;
  x0 += x1; x1 = rotl32(x1, 13); x1 ^= x0;
  x0 += x1; x1 = rotl32(x1, 15); x1 ^= x0;
  x0 += x1; x1 = rotl32(x1, 26); x1 ^= x0;
  x0 += x1; x1 = rotl32(x1, 6);  x1 ^= x0;
  x0 += ks2; x1 += k0 + 5u;
  return TF2{x0, x1};
}

// jax.random.key(42) = (0,42); split with jax_threefry_partitionable=True:
// subkey i = threefry(key, counter=(0, i)).
constexpr TF2 KEY_FG = threefry2x32(0u, 42u, 0u, 0u);
constexpr TF2 KEY_BG = threefry2x32(0u, 42u, 0u, 1u);

// 32-bit draw at flat index i (partitionable): bits = out.a ^ out.b of
// threefry(key, hi32(i)=0, lo32(i)=i). Ranking score for uniform() is
// monotone+injective in bits>>9, so compare the 23-bit value directly.
__device__ inline uint32_t rand23(uint32_t k0, uint32_t k1, uint32_t idx) {
  TF2 r = threefry2x32(k0, k1, 0u, idx);
  return (r.a ^ r.b) >> 9;
}

// ---------------- geometry ----------------
__device__ inline void anchor_of(int n, float& x1, float& y1, float& x2, float& y2) {
  int a = n % NA;
  int s = n / NA;
  int xx = s % NW;
  int yy = s / NW;
  float sx = (float)(xx * 16);
  float sy = (float)(yy * 16);
  x1 = c_anch[a][0] + sx; y1 = c_anch[a][1] + sy;
  x2 = c_anch[a][2] + sx; y2 = c_anch[a][3] + sy;
}

__device__ inline float iou1(float ax1, float ay1, float ax2, float ay2,
                             float gx1, float gy1, float gx2, float gy2) {
  float iw = fminf(ax2, gx2) - fmaxf(ax1, gx1) + 1.0f;
  iw = fmaxf(iw, 0.0f);
  float ih = fminf(ay2, gy2) - fmaxf(ay1, gy1) + 1.0f;
  ih = fmaxf(ih, 0.0f);
  float inter = iw * ih;
  float aa = (ax2 - ax1 + 1.0f) * (ay2 - ay1 + 1.0f);
  float ga = (gx2 - gx1 + 1.0f) * (gy2 - gy1 + 1.0f);
  return inter / (aa + ga - inter);
}

// ---------------- K1: per-gt max IoU, pruned to overlapping cells -------
// Anchors with no box overlap have iou exactly 0 and cannot affect the max
// (if the pruned max is 0, the reference's gt_max==0 -> 1e-5 replacement
// makes the best-check vacuous anyway). Per anchor type, overlapping shift
// cells form a rectangle; scan it with pow2-padded rows (shift/mask index
// math, conservative +/-1 cell margin). ~6.5K cells/gt vs 36864 brute.
__global__ __launch_bounds__(256) void k_gtmax(const float* __restrict__ gt,
                                               const int* __restrict__ nbox,
                                               float* __restrict__ gtmax) {
  int b = blockIdx.x / NK;
  int k = blockIdx.x % NK;
  if (k >= nbox[b]) {
    if (threadIdx.x == 0) gtmax[blockIdx.x] = -1.0f;  // unused downstream
    return;
  }
  const float* g = gt + ((size_t)b * NK + k) * 5;
  float gx1 = g[0], gy1 = g[1], gx2 = g[2], gy2 = g[3];
  float m = 0.0f;  // iou >= 0; empty scan -> 0 -> 1e-5 below
#pragma unroll
  for (int a = 0; a < NA; ++a) {
    float bx1 = c_anch[a][0], by1 = c_anch[a][1];
    float bx2 = c_anch[a][2], by2 = c_anch[a][3];
    // overlap needs 16*ix > gx1-1-bx2  and  16*ix < gx2+1-bx1 (cons. +/-1)
    int ix_lo = max(0, (int)floorf((gx1 - 1.0f - bx2) * 0.0625f) - 1);
    int ix_hi = min(NW - 1, (int)ceilf((gx2 + 1.0f - bx1) * 0.0625f) + 1);
    int iy_lo = max(0, (int)floorf((gy1 - 1.0f - by2) * 0.0625f) - 1);
    int iy_hi = min(NH - 1, (int)ceilf((gy2 + 1.0f - by1) * 0.0625f) + 1);
    if (ix_lo > ix_hi || iy_lo > iy_hi) continue;
    int nx = ix_hi - ix_lo + 1;
    int ny = iy_hi - iy_lo + 1;
    int lg = 32 - __clz(nx - 1);        // nx<=64 -> lg<=6 (nx==1 -> lg=0)
    int tot = ny << lg;
    unsigned mask = (1u << lg) - 1u;
    for (int c = threadIdx.x; c < tot; c += 256) {
      int ixo = c & mask;
      if (ixo >= nx) continue;
      int ix = ix_lo + ixo;
      int iy = iy_lo + (c >> lg);
      float sx = (float)(ix * 16), sy = (float)(iy * 16);
      m = fmaxf(m, iou1(bx1 + sx, by1 + sy, bx2 + sx, by2 + sy, gx1, gy1, gx2, gy2));
    }
  }
  for (int o = 1; o < 64; o <<= 1) m = fmaxf(m, __shfl_xor(m, o));
  __shared__ float ws4[4];
  if ((threadIdx.x & 63) == 0) ws4[threadIdx.x >> 6] = m;
  __syncthreads();
  if (threadIdx.x == 0) {
    m = fmaxf(fmaxf(ws4[0], ws4[1]), fmaxf(ws4[2], ws4[3]));
    if (m == 0.0f) m = 1e-5f;  // reference: gt_max==0 -> 1e-5
    gtmax[blockIdx.x] = m;
  }
}

// ---------------- K2: IoU + labels + threefry score, packed write -------
// (R5 form, 1 anchor/thread — the 4-anchor variant regressed: VGPR pressure)
__global__ __launch_bounds__(256) void k_label(const float* __restrict__ gt,
                                               const int* __restrict__ nbox,
                                               const float* __restrict__ gtmax,
                                               const float* __restrict__ iminfo,
                                               unsigned* __restrict__ pkarr,
                                               int* __restrict__ amax) {
  int b = blockIdx.x / BLK_PER_B;                // block-uniform batch index
  int n = (blockIdx.x % BLK_PER_B) * 256 + threadIdx.x;
  __shared__ float sg[NK * 5];
  __shared__ float sgm[NK];
  __shared__ float sga[NK];
  if (threadIdx.x < NK * 5) sg[threadIdx.x] = gt[(size_t)b * NK * 5 + threadIdx.x];
  if (threadIdx.x < NK) sgm[threadIdx.x] = gtmax[b * NK + threadIdx.x];
  __syncthreads();
  if (threadIdx.x < NK) {
    float* gg = sg + threadIdx.x * 5;
    sga[threadIdx.x] = (gg[2] - gg[0] + 1.0f) * (gg[3] - gg[1] + 1.0f);
  }
  __syncthreads();

  float ax1, ay1, ax2, ay2;
  anchor_of(n, ax1, ay1, ax2, ay2);
  float aa = (ax2 - ax1 + 1.0f) * (ay2 - ay1 + 1.0f);
  int m = nbox[b];
  float best = -2.0f;
  int bi = 0;
  bool isbest = false;
  for (int k = 0; k < m; ++k) {
    float iw = fminf(ax2, sg[k * 5 + 2]) - fmaxf(ax1, sg[k * 5]) + 1.0f;
    iw = fmaxf(iw, 0.0f);
    float ih = fminf(ay2, sg[k * 5 + 3]) - fmaxf(ay1, sg[k * 5 + 1]) + 1.0f;
    ih = fmaxf(ih, 0.0f);
    float inter = iw * ih;
    float ov = inter / (aa + sga[k] - inter);
    if (ov > best) { best = ov; bi = k; }   // first-max wins, like argmax
    if (ov == sgm[k]) isbest = true;
  }
  float imh = iminfo[0], imw = iminfo[1];  // im_info[0] used for all batches (matches ref)
  bool inside = (ax1 >= 0.0f) && (ay1 >= 0.0f) && (ax2 < imw) && (ay2 < imh);
  int lab = -1;
  if (inside) {
    if (best < 0.3f) lab = 0;
    if (isbest) lab = 1;
    if (best >= 0.7f) lab = 1;
  }
  int t = b * NN + n;
  uint32_t kk0 = (lab == 1) ? KEY_FG.a : KEY_BG.a;
  uint32_t kk1 = (lab == 1) ? KEY_FG.b : KEY_BG.b;
  uint32_t v = rand23(kk0, kk1, (uint32_t)t);
  pkarr[t] = (v << 2) | (uint32_t)(lab + 1);
  amax[t] = bi;
}

// ---------------- K3: threshold-only top-C selection (READ-ONLY) --------
// One 1024-thread block per BATCH (fg+bg fused; single P1 read serves both
// histograms). Kept-set closed form: anchor of class c kept iff
//   v > v*  ||  (v == v* && n <= i*)
// where (v*,i*) is the (C-1)-ranked element by (v desc, n asc) — located
// via 4096-bucket histogram + tie-list rank. Sentinel (0, 0x7FFFFFFF)
// keeps everything when total <= C. Output: thr[b] = {vfg,ifg,vbg,ibg},
// numex[b]. No pkarr writes at all; k_out applies the rule inline.
__global__ __launch_bounds__(1024) void k_select(const unsigned* __restrict__ pkarr,
                                                 float* __restrict__ numex,
                                                 uint4* __restrict__ thr) {
  int b = blockIdx.x;
  int base_lab = b * NN;
  int tid = threadIdx.x;

  __shared__ unsigned hF[4096];
  __shared__ unsigned hB[4096];
  __shared__ unsigned listV[2][1024];
  __shared__ unsigned listI[2][1024];
  __shared__ unsigned waveTot[4];
  __shared__ int sFG, sBG, sCross, sBs[2], sR1[2];
  __shared__ unsigned sCnt[2];
  __shared__ unsigned sV[2], sI[2];
  for (int i = tid; i < 4096; i += 1024) { hF[i] = 0; hB[i] = 0; }
  if (tid == 0) { sFG = 0; sBG = 0; sCnt[0] = 0; sCnt[1] = 0; }
  __syncthreads();

  const uint4* pk4 = (const uint4*)(pkarr + base_lab);

  // ---- Pass 1: fg/bg counts + both level-1 histograms ----
  int cfg = 0, cbg = 0;
  for (int i = tid; i < NN / 4; i += 1024) {
    uint4 P4 = pk4[i];
    unsigned pks[4] = {P4.x, P4.y, P4.z, P4.w};
#pragma unroll
    for (int j = 0; j < 4; ++j) {
      unsigned code = pks[j] & 3u;
      cfg += (code == 2u);
      cbg += (code == 1u);
      if (code == 2u) atomicAdd(&hF[pks[j] >> 13], 1u);
      else if (code == 1u) atomicAdd(&hB[pks[j] >> 13], 1u);
    }
  }
  for (int o = 1; o < 64; o <<= 1) { cfg += __shfl_xor(cfg, o); cbg += __shfl_xor(cbg, o); }
  if ((tid & 63) == 0) { atomicAdd(&sFG, cfg); atomicAdd(&sBG, cbg); }
  __syncthreads();

  int fg = sFG, bg = sBG;
  int fgk = min(fg, 128);
  int Cf = 128;
  int Cb = 256 - fgk;
  if (tid == 0) numex[b] = (float)(fgk + min(bg, Cb));
  bool actF = fg > Cf;
  bool actB = bg > Cb;
  if (!actF && !actB) {
    if (tid == 0) *(&thr[b]) = make_uint4(0u, 0x7FFFFFFFu, 0u, 0x7FFFFFFFu);
    return;  // uniform exit
  }

  // ---- Threshold bucket per active class (suffix-scan over 4096) ----
  for (int cls = 0; cls < 2; ++cls) {
    bool act = (cls == 0) ? actF : actB;
    if (!act) continue;
    const unsigned* h = (cls == 0) ? hF : hB;
    unsigned C = (unsigned)((cls == 0) ? Cf : Cb);
    if (tid == 0) sCross = -1;
    __syncthreads();
    unsigned myChunk = 0, suf = 0;
    if (tid < 256) {
      for (int j = 0; j < 16; ++j) myChunk += h[tid * 16 + j];
      unsigned ss = myChunk;
      int lane = tid & 63;
#pragma unroll
      for (int o = 1; o < 64; o <<= 1) {
        unsigned t2 = __shfl_down(ss, o);
        if (lane + o < 64) ss += t2;
      }
      suf = ss;
      if (lane == 0) waveTot[tid >> 6] = ss;
    }
    __syncthreads();
    if (tid < 256) {
      int w = tid >> 6;
      for (int w2 = w + 1; w2 < 4; ++w2) suf += waveTot[w2];
      if (suf >= C) atomicMax(&sCross, tid);  // suf = count in buckets >= 16*tid
    }
    __syncthreads();
    if (tid == sCross) {
      unsigned cum = suf - myChunk;  // count in buckets >= 16*(tid+1)
      int i = tid * 16 + 15;
      for (;; --i) {
        unsigned c = h[i];
        if (cum + c >= C) break;
        cum += c;
      }
      sBs[cls] = i; sR1[cls] = (int)(C - cum);
    }
    __syncthreads();
  }

  // ---- Pass 2: collect threshold-bucket ties for both classes ----
  int BsF = actF ? sBs[0] : -1;
  int BsB = actB ? sBs[1] : -1;
  for (int i = tid; i < NN / 4; i += 1024) {
    uint4 P4 = pk4[i];
    unsigned pks[4] = {P4.x, P4.y, P4.z, P4.w};
#pragma unroll
    for (int j = 0; j < 4; ++j) {
      unsigned code = pks[j] & 3u;
      int bk = (int)(pks[j] >> 13);
      int cls = -1;
      if (code == 2u && bk == BsF) cls = 0;
      else if (code == 1u && bk == BsB) cls = 1;
      if (cls >= 0) {
        unsigned p = atomicAdd(&sCnt[cls], 1u);
        if (p < 1024u) { listV[cls][p] = pks[j] >> 2; listI[cls][p] = (unsigned)(4 * i + j); }
      }
    }
  }
  __syncthreads();

  // ---- Find the r1-th tie (v desc, idx asc) per class: that's (v*,i*) ----
  for (int cls = 0; cls < 2; ++cls) {
    bool act = (cls == 0) ? actF : actB;
    if (!act) continue;
    unsigned L = min(sCnt[cls], 1024u);
    unsigned target = (unsigned)(sR1[cls] - 1);
    for (unsigned i = tid; i < L; i += 1024) {
      unsigned vi = listV[cls][i], xi = listI[cls][i];
      unsigned rank = 0;
      for (unsigned j = 0; j < L; ++j) {
        unsigned vj = listV[cls][j], xj = listI[cls][j];
        rank += (vj > vi) || (vj == vi && xj < xi);
      }
      if (rank == target) { sV[cls] = vi; sI[cls] = xi; }  // single writer
    }
  }
  __syncthreads();
  if (tid == 0) {
    uint4 t;
    t.x = actF ? sV[0] : 0u;  t.y = actF ? sI[0] : 0x7FFFFFFFu;
    t.z = actB ? sV[1] : 0u;  t.w = actB ? sI[1] : 0x7FFFFFFFu;
    thr[b] = t;
  }
}

// ---------------- K4: outputs with inline demotion (float4 stores) ------
__global__ __launch_bounds__(256) void k_out(const float* __restrict__ gt,
                                             const unsigned* __restrict__ pkarr,
                                             const int* __restrict__ amax,
                                             const float* __restrict__ iminfo,
                                             const float* __restrict__ numex,
                                             const uint4* __restrict__ thr,
                                             float* __restrict__ out) {
  int q = blockIdx.x * 256 + threadIdx.x;
  if (q >= (int)(OUT_TGT / 4)) return;
  int xx4 = q & 15;
  int yy = (q >> 4) & 63;
  int ba = q >> 10;
  int a = ba % NA;
  int b = ba / NA;
  int xx0 = xx4 * 4;
  int yx0 = yy * NW + xx0;

  float imh = iminfo[0], imw = iminfo[1];
  float inv_ne = 1.0f / numex[b];
  uint4 th = thr[b];

  float labf[4], iwv[4], owv[4], tg[4][4];
#pragma unroll
  for (int u = 0; u < 4; ++u) {
    int xx = xx0 + u;
    int n = (yy * NW + xx) * NA + a;
    int bn = b * NN + n;
    unsigned pk = pkarr[bn];
    int lab = (int)(pk & 3u) - 1;
    if (lab >= 0) {  // apply top-C demotion inline
      unsigned v = pk >> 2;
      unsigned vs = (lab == 1) ? th.x : th.z;
      unsigned is = (lab == 1) ? th.y : th.w;
      bool keep = (v > vs) || (v == vs && (unsigned)n <= is);
      if (!keep) lab = -1;
    }
    labf[u] = (float)lab;
    float ax1, ay1, ax2, ay2;
    anchor_of(n, ax1, ay1, ax2, ay2);
    bool inside = (ax1 >= 0.0f) && (ay1 >= 0.0f) && (ax2 < imw) && (ay2 < imh);
    float t0 = 0.f, t1 = 0.f, t2 = 0.f, t3 = 0.f;
    if (inside) {
      const float* g = gt + ((size_t)b * NK + amax[bn]) * 5;
      float ew = ax2 - ax1 + 1.0f, eh = ay2 - ay1 + 1.0f;
      float ecx = ax1 + 0.5f * ew, ecy = ay1 + 0.5f * eh;
      float gw = g[2] - g[0] + 1.0f, gh = g[3] - g[1] + 1.0f;
      float gcx = g[0] + 0.5f * gw, gcy = g[1] + 0.5f * gh;
      t0 = (gcx - ecx) / ew;
      t1 = (gcy - ecy) / eh;
      t2 = logf(gw / ew);
      t3 = logf(gh / eh);
    }
    tg[0][u] = t0; tg[1][u] = t1; tg[2][u] = t2; tg[3][u] = t3;
    iwv[u] = (lab == 1) ? 1.0f : 0.0f;
    owv[u] = (lab >= 0) ? inv_ne : 0.0f;
  }

  *(float4*)(out + OUT_LAB + (size_t)ba * HWSZ + yx0) =
      make_float4(labf[0], labf[1], labf[2], labf[3]);
  size_t tb = OUT_TGT + ((size_t)b * NA * 4 + a * 4) * HWSZ + yx0;
#pragma unroll
  for (int d = 0; d < 4; ++d)
    *(float4*)(out + tb + (size_t)d * HWSZ) =
        make_float4(tg[d][0], tg[d][1], tg[d][2], tg[d][3]);
  size_t ib = OUT_INW + ((size_t)b * NA * 4 + a * 4) * HWSZ + yx0;
  float4 iw4 = make_float4(iwv[0], iwv[1], iwv[2], iwv[3]);
#pragma unroll
  for (int d = 0; d < 4; ++d) *(float4*)(out + ib + (size_t)d * HWSZ) = iw4;
  size_t ob = OUT_OUTW + ((size_t)b * NA * 4 + a * 4) * HWSZ + yx0;
  float4 ow4 = make_float4(owv[0], owv[1], owv[2], owv[3]);
#pragma unroll
  for (int d = 0; d < 4; ++d) *(float4*)(out + ob + (size_t)d * HWSZ) = ow4;
}

extern "C" void kernel_launch(void* const* d_in, const int* in_sizes, int n_in,
                              void* d_out, int out_size, void* d_ws, size_t ws_size,
                              hipStream_t stream) {
  (void)in_sizes; (void)n_in; (void)out_size; (void)ws_size;
  const float* gt     = (const float*)d_in[1];  // (B,K,5)
  const float* iminfo = (const float*)d_in[2];  // (B,3)
  const int*   nbox   = (const int*)d_in[3];    // (B,)
  float* out = (float*)d_out;
  char* ws = (char*)d_ws;

  int*      amax  = (int*)(ws + OFF_AMAX);
  unsigned* pkarr = (unsigned*)(ws + OFF_PK);
  float*    gtmax = (float*)(ws + OFF_GTMAX);
  float*    numex = (float*)(ws + OFF_NUMEX);
  uint4*    thr   = (uint4*)(ws + OFF_THR);

  k_gtmax<<<NBATCH * NK, 256, 0, stream>>>(gt, nbox, gtmax);
  k_label<<<BN / 256, 256, 0, stream>>>(gt, nbox, gtmax, iminfo, pkarr, amax);
  k_select<<<NBATCH, 1024, 0, stream>>>(pkarr, numex, thr);
  k_out<<<(int)(OUT_TGT / 4 / 256), 256, 0, stream>>>(gt, pkarr, amax, iminfo, numex, thr, out);
}

// Round 8
// 145.249 us; speedup vs baseline: 1.1636x; 1.1209x over previous
//
#include <hip/hip_runtime.h>
#include <stdint.h>

// Exactness: the numpy/jax reference does plain IEEE f32 ops (no FMA
// contraction). hipcc defaults to -ffp-contract=fast; disable globally so
// IoU values match the reference bit-for-bit (labels depend on exact
// comparisons vs 0.3/0.7 and on ov == gt_max equality).
#pragma clang fp contract(off)

#define NBATCH 32
#define NK 50
#define NH 64
#define NW 64
#define NA 9
#define NN (NH * NW * NA)   // 36864 anchors per batch
#define BN (NBATCH * NN)    // 1179648
#define HWSZ (NH * NW)      // 4096

// ---------------- workspace layout (bytes) ----------------
// TYPE-MAJOR pk/amax: t' = b*NN + a*4096 + yx  (yx = yy*64+xx).
// pk[t'] = (v23 << 2) | (lab+1); v23 keyed by ORIGINAL n = yx*9+a.
// Coalesced writes in k_label, uint4 loads in k_select/k_out.
constexpr size_t OFF_AMAX  = 0;
constexpr size_t OFF_PK    = OFF_AMAX + (size_t)BN * 4;
constexpr size_t OFF_GTMAX = OFF_PK + (size_t)BN * 4;
constexpr size_t OFF_NUMEX = OFF_GTMAX + (size_t)NBATCH * NK * 4;
constexpr size_t OFF_THR   = OFF_NUMEX + (size_t)NBATCH * 4;

// ---------------- output layout (f32 elements) ----------------
constexpr size_t OUT_LAB  = 0;
constexpr size_t OUT_TGT  = (size_t)NBATCH * NA * HWSZ;                 // 1179648
constexpr size_t OUT_INW  = OUT_TGT + (size_t)NBATCH * NA * 4 * HWSZ;   // 5898240
constexpr size_t OUT_OUTW = OUT_INW + (size_t)NBATCH * NA * 4 * HWSZ;   // 10616832

// 9 base anchors, py-faster-rcnn generate_anchors(16, (0.5,1,2), (8,16,32)),
// ratio-major scale-minor. All integer-valued -> exact in f32.
__constant__ float c_anch[NA][4] = {
    {-84.f, -40.f, 99.f, 55.f},    {-176.f, -88.f, 191.f, 103.f},
    {-360.f, -184.f, 375.f, 199.f}, {-56.f, -56.f, 71.f, 71.f},
    {-120.f, -120.f, 135.f, 135.f}, {-248.f, -248.f, 263.f, 263.f},
    {-36.f, -80.f, 51.f, 95.f},    {-80.f, -168.f, 95.f, 183.f},
    {-168.f, -344.f, 183.f, 359.f}};

// ---------------- Threefry-2x32 (JAX convention) ----------------
struct TF2 { uint32_t a, b; };

__host__ __device__ constexpr uint32_t rotl32(uint32_t x, int d) {
  return (x << d) | (x >> (32 - d));
}

__host__ __device__ constexpr TF2 threefry2x32(uint32_t k0, uint32_t k1,
                                               uint32_t x0, uint32_t x1) {
  uint32_t ks2 = k0 ^ k1 ^ 0x1BD11BDAu;
  x0 += k0; x1 += k1;
  x0 += x1; x1 = rotl32(x1, 13); x1 ^= x0;
  x0 += x1; x1 = rotl32(x1, 15); x1 ^= x0;
  x0 += x1; x1 = rotl32(x1, 26); x1 ^= x0;
  x0 += x1; x1 = rotl32(x1, 6);  x1 ^= x0;
  x0 += k1; x1 += ks2 + 1u;
  x0 += x1; x1 = rotl32(x1, 17); x1 ^= x0;
  x0 += x1; x1 = rotl32(x1, 29); x1 ^= x0;
  x0 += x1; x1 = rotl32(x1, 16); x1 ^= x0;
  x0 += x1; x1 = rotl32(x1, 24); x1 ^= x0;
  x0 += ks2; x1 += k0 + 2u;
  x0 += x1; x1 = rotl32(x1, 13); x1 ^= x0;
  x0 += x1; x1 = rotl32(x1, 15); x1 ^= x0;
  x0 += x1; x1 = rotl32(x1, 26); x1 ^= x0;
  x0 += x1; x1 = rotl32(x1, 6);  x1 ^= x0;
  x0 += k0; x1 += k1 + 3u;
  x0 += x1; x1 = rotl32(x1, 17); x1 ^= x0;
  x0 += x1; x1 = rotl32(x1, 29); x1 ^= x0;
  x0 += x1; x1 = rotl32(x1, 16); x1 ^= x0;
  x0 += x1; x1 = rotl32(x1, 24); x1 ^= x0;
  x0 += k1; x1 += ks2 + 4u;
  x0 += x1; x1 = rotl32(x1, 13); x1 ^= x0;
  x0 += x1; x1 = rotl32(x1, 15); x1 ^= x0;
  x0 += x1; x1 = rotl32(x1, 26); x1 ^= x0;
  x0 += x1; x1 = rotl32(x1, 6);  x1 ^= x0;
  x0 += ks2; x1 += k0 + 5u;
  return TF2{x0, x1};
}

// jax.random.key(42) = (0,42); split with jax_threefry_partitionable=True:
// subkey i = threefry(key, counter=(0, i)).
constexpr TF2 KEY_FG = threefry2x32(0u, 42u, 0u, 0u);
constexpr TF2 KEY_BG = threefry2x32(0u, 42u, 0u, 1u);

// 32-bit draw at flat index i (partitionable): bits = out.a ^ out.b of
// threefry(key, hi32(i)=0, lo32(i)=i). Ranking score for uniform() is
// monotone+injective in bits>>9, so compare the 23-bit value directly.
__device__ inline uint32_t rand23(uint32_t k0, uint32_t k1, uint32_t idx) {
  TF2 r = threefry2x32(k0, k1, 0u, idx);
  return (r.a ^ r.b) >> 9;
}

// ---------------- geometry ----------------
__device__ inline float iou1(float ax1, float ay1, float ax2, float ay2,
                             float gx1, float gy1, float gx2, float gy2) {
  float iw = fminf(ax2, gx2) - fmaxf(ax1, gx1) + 1.0f;
  iw = fmaxf(iw, 0.0f);
  float ih = fminf(ay2, gy2) - fmaxf(ay1, gy1) + 1.0f;
  ih = fmaxf(ih, 0.0f);
  float inter = iw * ih;
  float aa = (ax2 - ax1 + 1.0f) * (ay2 - ay1 + 1.0f);
  float ga = (gx2 - gx1 + 1.0f) * (gy2 - gy1 + 1.0f);
  return inter / (aa + ga - inter);
}

// ---------------- K1: per-gt max IoU, pruned to overlapping cells -------
// Anchors with no box overlap have iou exactly 0 and cannot affect the max
// (if the pruned max is 0, the reference's gt_max==0 -> 1e-5 replacement
// makes the best-check vacuous anyway). Per anchor type, overlapping shift
// cells form a rectangle; scan it with pow2-padded rows (shift/mask index
// math, conservative +/-1 cell margin). ~6.5K cells/gt vs 36864 brute.
__global__ __launch_bounds__(256) void k_gtmax(const float* __restrict__ gt,
                                               const int* __restrict__ nbox,
                                               float* __restrict__ gtmax) {
  int b = blockIdx.x / NK;
  int k = blockIdx.x % NK;
  if (k >= nbox[b]) {
    if (threadIdx.x == 0) gtmax[blockIdx.x] = -1.0f;  // unused downstream
    return;
  }
  const float* g = gt + ((size_t)b * NK + k) * 5;
  float gx1 = g[0], gy1 = g[1], gx2 = g[2], gy2 = g[3];
  float m = 0.0f;  // iou >= 0; empty scan -> 0 -> 1e-5 below
#pragma unroll
  for (int a = 0; a < NA; ++a) {
    float bx1 = c_anch[a][0], by1 = c_anch[a][1];
    float bx2 = c_anch[a][2], by2 = c_anch[a][3];
    // overlap needs 16*ix > gx1-1-bx2  and  16*ix < gx2+1-bx1 (cons. +/-1)
    int ix_lo = max(0, (int)floorf((gx1 - 1.0f - bx2) * 0.0625f) - 1);
    int ix_hi = min(NW - 1, (int)ceilf((gx2 + 1.0f - bx1) * 0.0625f) + 1);
    int iy_lo = max(0, (int)floorf((gy1 - 1.0f - by2) * 0.0625f) - 1);
    int iy_hi = min(NH - 1, (int)ceilf((gy2 + 1.0f - by1) * 0.0625f) + 1);
    if (ix_lo > ix_hi || iy_lo > iy_hi) continue;
    int nx = ix_hi - ix_lo + 1;
    int ny = iy_hi - iy_lo + 1;
    int lg = 32 - __clz(nx - 1);        // nx<=64 -> lg<=6 (nx==1 -> lg=0)
    int tot = ny << lg;
    unsigned mask = (1u << lg) - 1u;
    for (int c = threadIdx.x; c < tot; c += 256) {
      int ixo = c & mask;
      if (ixo >= nx) continue;
      int ix = ix_lo + ixo;
      int iy = iy_lo + (c >> lg);
      float sx = (float)(ix * 16), sy = (float)(iy * 16);
      m = fmaxf(m, iou1(bx1 + sx, by1 + sy, bx2 + sx, by2 + sy, gx1, gy1, gx2, gy2));
    }
  }
  for (int o = 1; o < 64; o <<= 1) m = fmaxf(m, __shfl_xor(m, o));
  __shared__ float ws4[4];
  if ((threadIdx.x & 63) == 0) ws4[threadIdx.x >> 6] = m;
  __syncthreads();
  if (threadIdx.x == 0) {
    m = fmaxf(fmaxf(ws4[0], ws4[1]), fmaxf(ws4[2], ws4[3]));
    if (m == 0.0f) m = 1e-5f;  // reference: gt_max==0 -> 1e-5
    gtmax[blockIdx.x] = m;
  }
}

// ---------------- K2: labels, type-major blocks + gt y-compaction -------
// One block = (batch, anchor-type, 4-row band of 256 cells). Wave 0
// ballot-compacts the <=50 gt boxes to those whose y-range can overlap the
// band (conservative +1 slack): skipped boxes have ov exactly 0, which
// cannot change max (best init 0, bi init 0 = argmax of all-zeros) nor the
// ov==gt_max check (gt_max > 0 always). ~4x fewer IoU iterations, and all
// global loads/stores coalesced in the type-major layout.
__global__ __launch_bounds__(256) void k_label(const float* __restrict__ gt,
                                               const int* __restrict__ nbox,
                                               const float* __restrict__ gtmax,
                                               const float* __restrict__ iminfo,
                                               unsigned* __restrict__ pk2,
                                               int* __restrict__ amax2) {
  int bid = blockIdx.x;           // 32 * 9 * 16 = 4608 blocks
  int b = bid / (NA * 16);
  int rem = bid - b * (NA * 16);
  int a = rem >> 4;
  int cell0 = (rem & 15) << 8;    // 256-cell band = rows (cell0>>6)..+3
  float bx1 = c_anch[a][0], by1 = c_anch[a][1];
  float bx2 = c_anch[a][2], by2 = c_anch[a][3];
  int tid = threadIdx.x;

  __shared__ float cx1[NK], cy1[NK], cx2[NK], cy2[NK], cga[NK], cgm[NK];
  __shared__ int ckk[NK];
  __shared__ int cN;
  if (tid < 64) {  // wave 0 compacts
    int m = nbox[b];
    bool keep = false;
    float gx1 = 0, gy1 = 0, gx2 = 0, gy2 = 0, gm = 0;
    if (tid < m) {
      const float* g = gt + ((size_t)b * NK + tid) * 5;
      gx1 = g[0]; gy1 = g[1]; gx2 = g[2]; gy2 = g[3];
      gm = gtmax[b * NK + tid];
      float sy0 = (float)((cell0 >> 6) << 4);
      float lo = fmaxf(by1 + sy0, gy1);
      float hi = fminf(by2 + sy0 + 48.0f, gy2);
      keep = (hi - lo + 2.0f) > 0.0f;  // band ih bound + slack 1
    }
    unsigned long long mk = __ballot(keep);
    if (keep) {
      int pos = (int)__popcll(mk & ((1ull << tid) - 1ull));
      cx1[pos] = gx1; cy1[pos] = gy1; cx2[pos] = gx2; cy2[pos] = gy2;
      cga[pos] = (gx2 - gx1 + 1.0f) * (gy2 - gy1 + 1.0f);
      cgm[pos] = gm; ckk[pos] = tid;
    }
    if (tid == 0) cN = (int)__popcll(mk);
  }
  __syncthreads();

  int cell = cell0 + tid;         // cell == yx (yy*64+xx)
  float sx = (float)((cell & 63) << 4);
  float sy = (float)((cell >> 6) << 4);
  float ax1 = bx1 + sx, ay1 = by1 + sy;
  float ax2 = bx2 + sx, ay2 = by2 + sy;
  // exact: (ax2-ax1) == (bx2-bx1) bitwise (all integer-valued f32)
  float aa = (bx2 - bx1 + 1.0f) * (by2 - by1 + 1.0f);
  float best = 0.0f;              // == max over all-zero ovs
  int bi = 0;                     // == argmax of all-zeros
  bool isbest = false;
  int M = cN;
  for (int j = 0; j < M; ++j) {
    float iw = fminf(ax2, cx2[j]) - fmaxf(ax1, cx1[j]) + 1.0f;
    iw = fmaxf(iw, 0.0f);
    float ih = fminf(ay2, cy2[j]) - fmaxf(ay1, cy1[j]) + 1.0f;
    ih = fmaxf(ih, 0.0f);
    float inter = iw * ih;
    float ov = inter / (aa + cga[j] - inter);
    if (ov > best) { best = ov; bi = ckk[j]; }  // first-max wins (k asc)
    isbest |= (ov == cgm[j]);
  }
  float imh = iminfo[0], imw = iminfo[1];  // im_info[0] for all batches (ref)
  bool inside = (ax1 >= 0.0f) && (ay1 >= 0.0f) && (ax2 < imw) && (ay2 < imh);
  int lab = -1;
  if (inside) {
    if (best < 0.3f) lab = 0;
    if (isbest) lab = 1;
    if (best >= 0.7f) lab = 1;
  }
  int n = cell * NA + a;                    // original anchor index
  uint32_t kk0 = (lab == 1) ? KEY_FG.a : KEY_BG.a;
  uint32_t kk1 = (lab == 1) ? KEY_FG.b : KEY_BG.b;
  uint32_t v = rand23(kk0, kk1, (uint32_t)(b * NN + n));
  int tp = b * NN + a * HWSZ + cell;        // type-major slot
  pk2[tp] = (v << 2) | (uint32_t)(lab + 1);
  amax2[tp] = bi;
}

// ---------------- K3: threshold-only top-C selection (READ-ONLY) --------
// One 1024-thread block per BATCH (fg+bg fused). Kept-set closed form:
// anchor of class c kept iff v > v* || (v == v* && n <= i*), where (v*,i*)
// is the (C-1)-ranked element by (v desc, n asc). Histogram pass is
// order-free so it reads the type-major layout linearly; original n is
// recovered only for threshold-bucket ties (n = (f&4095)*9 + (f>>12)).
__global__ __launch_bounds__(1024) void k_select(const unsigned* __restrict__ pk2,
                                                 float* __restrict__ numex,
                                                 uint4* __restrict__ thr) {
  int b = blockIdx.x;
  int base_lab = b * NN;
  int tid = threadIdx.x;

  __shared__ unsigned hF[4096];
  __shared__ unsigned hB[4096];
  __shared__ unsigned listV[2][1024];
  __shared__ unsigned listI[2][1024];
  __shared__ unsigned waveTot[4];
  __shared__ int sFG, sBG, sCross, sBs[2], sR1[2];
  __shared__ unsigned sCnt[2];
  __shared__ unsigned sV[2], sI[2];
  for (int i = tid; i < 4096; i += 1024) { hF[i] = 0; hB[i] = 0; }
  if (tid == 0) { sFG = 0; sBG = 0; sCnt[0] = 0; sCnt[1] = 0; }
  __syncthreads();

  const uint4* pk4 = (const uint4*)(pk2 + base_lab);

  // ---- Pass 1: fg/bg counts + both level-1 histograms ----
  int cfg = 0, cbg = 0;
  for (int i = tid; i < NN / 4; i += 1024) {
    uint4 P4 = pk4[i];
    unsigned pks[4] = {P4.x, P4.y, P4.z, P4.w};
#pragma unroll
    for (int j = 0; j < 4; ++j) {
      unsigned code = pks[j] & 3u;
      cfg += (code == 2u);
      cbg += (code == 1u);
      if (code == 2u) atomicAdd(&hF[pks[j] >> 13], 1u);
      else if (code == 1u) atomicAdd(&hB[pks[j] >> 13], 1u);
    }
  }
  for (int o = 1; o < 64; o <<= 1) { cfg += __shfl_xor(cfg, o); cbg += __shfl_xor(cbg, o); }
  if ((tid & 63) == 0) { atomicAdd(&sFG, cfg); atomicAdd(&sBG, cbg); }
  __syncthreads();

  int fg = sFG, bg = sBG;
  int fgk = min(fg, 128);
  int Cf = 128;
  int Cb = 256 - fgk;
  if (tid == 0) numex[b] = (float)(fgk + min(bg, Cb));
  bool actF = fg > Cf;
  bool actB = bg > Cb;
  if (!actF && !actB) {
    if (tid == 0) thr[b] = make_uint4(0u, 0x7FFFFFFFu, 0u, 0x7FFFFFFFu);
    return;  // uniform exit
  }

  // ---- Threshold bucket per active class (suffix-scan over 4096) ----
  for (int cls = 0; cls < 2; ++cls) {
    bool act = (cls == 0) ? actF : actB;
    if (!act) continue;
    const unsigned* h = (cls == 0) ? hF : hB;
    unsigned C = (unsigned)((cls == 0) ? Cf : Cb);
    if (tid == 0) sCross = -1;
    __syncthreads();
    unsigned myChunk = 0, suf = 0;
    if (tid < 256) {
      for (int j = 0; j < 16; ++j) myChunk += h[tid * 16 + j];
      unsigned ss = myChunk;
      int lane = tid & 63;
#pragma unroll
      for (int o = 1; o < 64; o <<= 1) {
        unsigned t2 = __shfl_down(ss, o);
        if (lane + o < 64) ss += t2;
      }
      suf = ss;
      if (lane == 0) waveTot[tid >> 6] = ss;
    }
    __syncthreads();
    if (tid < 256) {
      int w = tid >> 6;
      for (int w2 = w + 1; w2 < 4; ++w2) suf += waveTot[w2];
      if (suf >= C) atomicMax(&sCross, tid);  // suf = count in buckets >= 16*tid
    }
    __syncthreads();
    if (tid == sCross) {
      unsigned cum = suf - myChunk;  // count in buckets >= 16*(tid+1)
      int i = tid * 16 + 15;
      for (;; --i) {
        unsigned c = h[i];
        if (cum + c >= C) break;
        cum += c;
      }
      sBs[cls] = i; sR1[cls] = (int)(C - cum);
    }
    __syncthreads();
  }

  // ---- Pass 2: collect threshold-bucket ties (original n as index) ----
  int BsF = actF ? sBs[0] : -1;
  int BsB = actB ? sBs[1] : -1;
  for (int i = tid; i < NN / 4; i += 1024) {
    uint4 P4 = pk4[i];
    unsigned pks[4] = {P4.x, P4.y, P4.z, P4.w};
#pragma unroll
    for (int j = 0; j < 4; ++j) {
      unsigned code = pks[j] & 3u;
      int bk = (int)(pks[j] >> 13);
      int cls = -1;
      if (code == 2u && bk == BsF) cls = 0;
      else if (code == 1u && bk == BsB) cls = 1;
      if (cls >= 0) {
        int f = 4 * i + j;                       // type-major offset
        unsigned n = (unsigned)((f & 4095) * NA + (f >> 12));
        unsigned p = atomicAdd(&sCnt[cls], 1u);
        if (p < 1024u) { listV[cls][p] = pks[j] >> 2; listI[cls][p] = n; }
      }
    }
  }
  __syncthreads();

  // ---- Find the r1-th tie (v desc, n asc) per class: that's (v*,i*) ----
  for (int cls = 0; cls < 2; ++cls) {
    bool act = (cls == 0) ? actF : actB;
    if (!act) continue;
    unsigned L = min(sCnt[cls], 1024u);
    unsigned target = (unsigned)(sR1[cls] - 1);
    for (unsigned i = tid; i < L; i += 1024) {
      unsigned vi = listV[cls][i], xi = listI[cls][i];
      unsigned rank = 0;
      for (unsigned j = 0; j < L; ++j) {
        unsigned vj = listV[cls][j], xj = listI[cls][j];
        rank += (vj > vi) || (vj == vi && xj < xi);
      }
      if (rank == target) { sV[cls] = vi; sI[cls] = xi; }  // single writer
    }
  }
  __syncthreads();
  if (tid == 0) {
    uint4 t;
    t.x = actF ? sV[0] : 0u;  t.y = actF ? sI[0] : 0x7FFFFFFFu;
    t.z = actB ? sV[1] : 0u;  t.w = actB ? sI[1] : 0x7FFFFFFFu;
    thr[b] = t;
  }
}

// ---------------- K4: outputs, fully-coalesced uint4/int4 loads ---------
__global__ __launch_bounds__(256) void k_out(const float* __restrict__ gt,
                                             const unsigned* __restrict__ pk2,
                                             const int* __restrict__ amax2,
                                             const float* __restrict__ iminfo,
                                             const float* __restrict__ numex,
                                             const uint4* __restrict__ thr,
                                             float* __restrict__ out) {
  int q = blockIdx.x * 256 + threadIdx.x;
  if (q >= (int)(OUT_TGT / 4)) return;
  int xx4 = q & 15;
  int yy = (q >> 4) & 63;
  int ba = q >> 10;
  int a = ba % NA;
  int b = ba / NA;
  int xx0 = xx4 * 4;
  int yx0 = yy * NW + xx0;

  float imh = iminfo[0], imw = iminfo[1];
  float inv_ne = 1.0f / numex[b];
  uint4 th = thr[b];

  int t4 = ba * HWSZ + yx0;                 // == b*NN + a*4096 + yx0
  uint4 pkq = *(const uint4*)(pk2 + t4);
  int4 amq = *(const int4*)(amax2 + t4);
  unsigned pkv[4] = {pkq.x, pkq.y, pkq.z, pkq.w};
  int amv[4] = {amq.x, amq.y, amq.z, amq.w};

  float bx1 = c_anch[a][0], by1 = c_anch[a][1];
  float bx2 = c_anch[a][2], by2 = c_anch[a][3];
  float sy = (float)(yy * 16);

  float labf[4], iwv[4], owv[4], tg[4][4];
#pragma unroll
  for (int u = 0; u < 4; ++u) {
    int xx = xx0 + u;
    int n = (yy * NW + xx) * NA + a;
    unsigned pk = pkv[u];
    int lab = (int)(pk & 3u) - 1;
    if (lab >= 0) {  // apply top-C demotion inline
      unsigned v = pk >> 2;
      unsigned vs = (lab == 1) ? th.x : th.z;
      unsigned is = (lab == 1) ? th.y : th.w;
      bool keep = (v > vs) || (v == vs && (unsigned)n <= is);
      if (!keep) lab = -1;
    }
    labf[u] = (float)lab;
    float sx = (float)(xx * 16);
    float ax1 = bx1 + sx, ay1 = by1 + sy, ax2 = bx2 + sx, ay2 = by2 + sy;
    bool inside = (ax1 >= 0.0f) && (ay1 >= 0.0f) && (ax2 < imw) && (ay2 < imh);
    float t0 = 0.f, t1 = 0.f, t2 = 0.f, t3 = 0.f;
    if (inside) {
      const float* g = gt + ((size_t)b * NK + amv[u]) * 5;
      float ew = ax2 - ax1 + 1.0f, eh = ay2 - ay1 + 1.0f;
      float ecx = ax1 + 0.5f * ew, ecy = ay1 + 0.5f * eh;
      float gw = g[2] - g[0] + 1.0f, gh = g[3] - g[1] + 1.0f;
      float gcx = g[0] + 0.5f * gw, gcy = g[1] + 0.5f * gh;
      t0 = (gcx - ecx) / ew;
      t1 = (gcy - ecy) / eh;
      t2 = logf(gw / ew);
      t3 = logf(gh / eh);
    }
    tg[0][u] = t0; tg[1][u] = t1; tg[2][u] = t2; tg[3][u] = t3;
    iwv[u] = (lab == 1) ? 1.0f : 0.0f;
    owv[u] = (lab >= 0) ? inv_ne : 0.0f;
  }

  *(float4*)(out + OUT_LAB + (size_t)ba * HWSZ + yx0) =
      make_float4(labf[0], labf[1], labf[2], labf[3]);
  size_t tb = OUT_TGT + ((size_t)b * NA * 4 + a * 4) * HWSZ + yx0;
#pragma unroll
  for (int d = 0; d < 4; ++d)
    *(float4*)(out + tb + (size_t)d * HWSZ) =
        make_float4(tg[d][0], tg[d][1], tg[d][2], tg[d][3]);
  size_t ib = OUT_INW + ((size_t)b * NA * 4 + a * 4) * HWSZ + yx0;
  float4 iw4 = make_float4(iwv[0], iwv[1], iwv[2], iwv[3]);
#pragma unroll
  for (int d = 0; d < 4; ++d) *(float4*)(out + ib + (size_t)d * HWSZ) = iw4;
  size_t ob = OUT_OUTW + ((size_t)b * NA * 4 + a * 4) * HWSZ + yx0;
  float4 ow4 = make_float4(owv[0], owv[1], owv[2], owv[3]);
#pragma unroll
  for (int d = 0; d < 4; ++d) *(float4*)(out + ob + (size_t)d * HWSZ) = ow4;
}

extern "C" void kernel_launch(void* const* d_in, const int* in_sizes, int n_in,
                              void* d_out, int out_size, void* d_ws, size_t ws_size,
                              hipStream_t stream) {
  (void)in_sizes; (void)n_in; (void)out_size; (void)ws_size;
  const float* gt     = (const float*)d_in[1];  // (B,K,5)
  const float* iminfo = (const float*)d_in[2];  // (B,3)
  const int*   nbox   = (const int*)d_in[3];    // (B,)
  float* out = (float*)d_out;
  char* ws = (char*)d_ws;

  int*      amax2 = (int*)(ws + OFF_AMAX);
  unsigned* pk2   = (unsigned*)(ws + OFF_PK);
  float*    gtmax = (float*)(ws + OFF_GTMAX);
  float*    numex = (float*)(ws + OFF_NUMEX);
  uint4*    thr   = (uint4*)(ws + OFF_THR);

  k_gtmax<<<NBATCH * NK, 256, 0, stream>>>(gt, nbox, gtmax);
  k_label<<<NBATCH * NA * 16, 256, 0, stream>>>(gt, nbox, gtmax, iminfo, pk2, amax2);
  k_select<<<NBATCH, 1024, 0, stream>>>(pk2, numex, thr);
  k_out<<<(int)(OUT_TGT / 4 / 256), 256, 0, stream>>>(gt, pk2, amax2, iminfo, numex, thr, out);
}